// Round 3
// baseline (269.299 us; speedup 1.0000x reference)
//
#include <hip/hip_runtime.h>

#define NN 50000
#define DD 128
#define NE 600000
#define NP 200000
#define NS 300000
#define NU 256
#define NW 12500    // NN/4 int4 words
#define NB64 782    // ceil(NN/64)
#define NSCAN 49    // ceil(NW/256) scan blocks
#define BBK 256     // bucket-role blocks
#define EPB2 2344   // ceil(NE/BBK)

typedef __attribute__((ext_vector_type(8))) short short8;
typedef __attribute__((ext_vector_type(4))) float floatx4;

__device__ inline float bf2f(unsigned int u16) {
    unsigned int x = u16 << 16;
    float f; __builtin_memcpy(&f, &x, 4); return f;
}
__device__ inline unsigned short f2bf(float f) {
    unsigned int x; __builtin_memcpy(&x, &f, 4);
    unsigned int lsb = (x >> 16) & 1u;
    x += 0x7fffu + lsb;
    return (unsigned short)(x >> 16);
}

// ---- zero degree counters + lookback status (workspace is re-poisoned) ----
__global__ __launch_bounds__(256) void k_prep(int* __restrict__ deg,
                                              unsigned long long* __restrict__ status) {
    int gid = blockIdx.x * 256 + threadIdx.x;
    if (gid < 64) status[gid] = 0ull;
    if (gid < 2 * NW) ((int4*)deg)[gid] = (int4){0, 0, 0, 0};   // 100000 ints
}

// ---- degree build: 1.2M global atomics (L2-resolved, cheap on CDNA4) ----
// deg[0..NN) = out-degree (src counts), deg[NN..2NN) = in-degree (dst counts)
__global__ __launch_bounds__(256) void k_deg(const int* __restrict__ ei,
                                             int* __restrict__ deg) {
    int nt = gridDim.x * 256;
    for (int w = blockIdx.x * 256 + threadIdx.x; w < 2 * NE / 4; w += nt) {
        int4 e = ((const int4*)ei)[w];
        int base = (w >= NE / 4) ? NN : 0;   // NE%4==0: word never straddles halves
        atomicAdd(&deg[base + e.x], 1);
        atomicAdd(&deg[base + e.y], 1);
        atomicAdd(&deg[base + e.z], 1);
        atomicAdd(&deg[base + e.w], 1);
    }
}

// ---- scan: row_ptr (exclusive prefix of in-degree) + cursor copy + rsqrt r's
// + weight bf16 transpose-cast (hides under the wave-parallel lookback wait) ----
__global__ __launch_bounds__(256) void k_scan(
    const int* __restrict__ deg, float* __restrict__ r,
    int* __restrict__ row_ptr, int* __restrict__ cur,
    unsigned long long* __restrict__ status,
    const float* __restrict__ W1, const float* __restrict__ W2,
    const float* __restrict__ dW,
    unsigned short* __restrict__ BT1, unsigned short* __restrict__ BT2,
    unsigned short* __restrict__ BTd)
{
    int b = blockIdx.x, tid = threadIdx.x, lane = tid & 63, w = tid >> 6;
    int gid = b * 256 + tid;

    int4 v = {0, 0, 0, 0};
    if (gid < NW) {
        int4 din  = ((const int4*)(deg + NN))[gid];
        int4 dout = ((const int4*)deg)[gid];
        v = din;
        float4 ri = {rsqrtf((float)max(din.x, 1)),  rsqrtf((float)max(din.y, 1)),
                     rsqrtf((float)max(din.z, 1)),  rsqrtf((float)max(din.w, 1))};
        float4 ro = {rsqrtf((float)max(dout.x, 1)), rsqrtf((float)max(dout.y, 1)),
                     rsqrtf((float)max(dout.z, 1)), rsqrtf((float)max(dout.w, 1))};
        *(float4*)(r + NN + gid * 4) = ri;
        *(float4*)(r + gid * 4) = ro;
    }

    // block-local scan of in-degrees
    __shared__ int wsum[4];
    __shared__ long long sbase;
    int tot = v.x + v.y + v.z + v.w;
    int x = tot;
#pragma unroll
    for (int off = 1; off < 64; off <<= 1) {
        int y = __shfl_up(x, off);
        if (lane >= off) x += y;
    }
    if (lane == 63) wsum[w] = x;
    __syncthreads();
    int woff = 0;
#pragma unroll
    for (int i = 0; i < 4; ++i) if (i < w) woff += wsum[i];
    if (w == 0) {
        int btot = wsum[0] + wsum[1] + wsum[2] + wsum[3];
        if (lane == 0) {
            __threadfence();
            atomicExch(&status[b], (1ull << 62) | (unsigned long long)btot);
        }
        // wave-parallel lookback: each lane polls one predecessor (49 < 64,
        // all blocks co-resident at grid=49)
        long long run = 0;
        if (lane < b) {
            unsigned long long s;
            do { s = atomicAdd(&status[lane], 0ull); } while (s == 0ull);
            run = (long long)(s & 0x3fffffffffffffffull);
        }
#pragma unroll
        for (int off = 32; off > 0; off >>= 1) run += __shfl_down(run, off);
        if (lane == 0) sbase = run;
    }
    // weight transpose + bf16 cast: independent work overlapping the lookback
    for (int t = gid; t < 65536; t += NSCAN * 256) {
        if (t < 16384) { int rr = t >> 7, cc = t & 127; BT1[cc * 128 + rr] = f2bf(W1[t]); }
        else if (t < 32768) { int t2 = t - 16384; int rr = t2 >> 7, cc = t2 & 127; BT2[cc * 128 + rr] = f2bf(W2[t2]); }
        else { int t2 = t - 32768; int rr = t2 >> 8, cc = t2 & 255; BTd[cc * 128 + rr] = f2bf(dW[t2]); }
    }
    __syncthreads();
    if (gid < NW) {
        int base = (int)sbase + woff + (x - tot);
        int4 o = {base, base + v.x, base + v.x + v.y, base + v.x + v.y + v.z};
        ((int4*)row_ptr)[gid] = o;
        ((int4*)cur)[gid] = o;     // atomic cursors for the bucket pass
    }
    if (b == 0 && tid == 0) row_ptr[NN] = NE;
}

// ---- wide kernel: blocks 0..BBK-1 bucket edges via global atomic cursors;
// blocks BBK.. do the layer-1 GEMM. Both depend only on k_scan. ----
__global__ __launch_bounds__(256) void k_gemm1_bucket(
    const float* __restrict__ A, const float* __restrict__ rs,
    const unsigned short* __restrict__ BT, unsigned short* __restrict__ Cm,
    const int* __restrict__ ei, int* __restrict__ cur, int* __restrict__ col)
{
    __shared__ unsigned short sm[26112];   // GEMM tiles (bucket role unused)
    int b = blockIdx.x, tid = threadIdx.x;

    if (b < BBK) {
        int e0 = b * EPB2, e1 = min(e0 + EPB2, NE);
        for (int e = e0 + tid; e < e1; e += 256) {
            int s = ei[e], d = ei[NE + e];
            int pos = atomicAdd(&cur[d], 1);
            col[pos] = s;
        }
        return;
    }

    // ---- GEMM role: t = (bf16(A_f32) @ W1) * r_out ----
    unsigned short (*As)[136] = (unsigned short(*)[136])sm;
    unsigned short (*Bs)[136] = (unsigned short(*)[136])(sm + 64 * 136);
    int lane = tid & 63, wave = tid >> 6;
    int quad = lane >> 4, l16 = lane & 15;
    int row0 = (b - BBK) * 64;

#pragma unroll
    for (int p = 0; p < 8; ++p) {
        int fid = tid + p * 256;
        int rr = fid >> 5, c = fid & 31;
        int gr = row0 + rr; if (gr > NN - 1) gr = NN - 1;
        float4 v = *(const float4*)(A + (size_t)gr * DD + c * 4);
        ushort4 u;
        u.x = f2bf(v.x); u.y = f2bf(v.y); u.z = f2bf(v.z); u.w = f2bf(v.w);
        *(ushort4*)&As[rr][c * 4] = u;
    }
#pragma unroll
    for (int p = 0; p < 8; ++p) {
        int fid = tid + p * 256;
        int rr = fid >> 4, c = fid & 15;
        *(uint4*)&Bs[rr][c * 8] = *(const uint4*)(BT + (size_t)rr * DD + c * 8);
    }
    __syncthreads();

    short8 af[4];
#pragma unroll
    for (int ks = 0; ks < 4; ++ks)
        af[ks] = *(const short8*)&As[wave * 16 + l16][ks * 32 + quad * 8];
    floatx4 acc[8];
#pragma unroll
    for (int nt = 0; nt < 8; ++nt) acc[nt] = (floatx4){0.f, 0.f, 0.f, 0.f};
#pragma unroll
    for (int ks = 0; ks < 4; ++ks) {
#pragma unroll
        for (int nt = 0; nt < 8; ++nt) {
            short8 bf = *(const short8*)&Bs[nt * 16 + l16][ks * 32 + quad * 8];
            acc[nt] = __builtin_amdgcn_mfma_f32_16x16x32_bf16(af[ks], bf, acc[nt], 0, 0, 0);
        }
    }
    int rbase = row0 + wave * 16 + quad * 4;
#pragma unroll
    for (int rr = 0; rr < 4; ++rr) {
        int gr = rbase + rr;
        if (gr < NN) {
            float s = rs[gr];
#pragma unroll
            for (int nt = 0; nt < 8; ++nt)
                Cm[(size_t)gr * DD + nt * 16 + l16] = f2bf(acc[nt][rr] * s);
        }
    }
}

// ---- MFMA GEMM (layer 2): Cm = rowscale(A_bf16 @ W2) ----
__global__ __launch_bounds__(256) void k_gemm_bf(const unsigned short* __restrict__ A,
                                                 const float* __restrict__ rs,
                                                 const unsigned short* __restrict__ BT,
                                                 unsigned short* __restrict__ Cm) {
    __shared__ unsigned short As[64][136];
    __shared__ unsigned short Bs[128][136];
    int tid = threadIdx.x, lane = tid & 63, wave = tid >> 6;
    int quad = lane >> 4, l16 = lane & 15;
    int row0 = blockIdx.x * 64;

#pragma unroll
    for (int p = 0; p < 4; ++p) {
        int fid = tid + p * 256;
        int rr = fid >> 4, c = fid & 15;
        int gr = row0 + rr; if (gr > NN - 1) gr = NN - 1;
        *(uint4*)&As[rr][c * 8] = *(const uint4*)(A + (size_t)gr * DD + c * 8);
    }
#pragma unroll
    for (int p = 0; p < 8; ++p) {
        int fid = tid + p * 256;
        int rr = fid >> 4, c = fid & 15;
        *(uint4*)&Bs[rr][c * 8] = *(const uint4*)(BT + (size_t)rr * DD + c * 8);
    }
    __syncthreads();

    short8 af[4];
#pragma unroll
    for (int ks = 0; ks < 4; ++ks)
        af[ks] = *(const short8*)&As[wave * 16 + l16][ks * 32 + quad * 8];
    floatx4 acc[8];
#pragma unroll
    for (int nt = 0; nt < 8; ++nt) acc[nt] = (floatx4){0.f, 0.f, 0.f, 0.f};
#pragma unroll
    for (int ks = 0; ks < 4; ++ks) {
#pragma unroll
        for (int nt = 0; nt < 8; ++nt) {
            short8 bf = *(const short8*)&Bs[nt * 16 + l16][ks * 32 + quad * 8];
            acc[nt] = __builtin_amdgcn_mfma_f32_16x16x32_bf16(af[ks], bf, acc[nt], 0, 0, 0);
        }
    }
    int rbase = row0 + wave * 16 + quad * 4;
#pragma unroll
    for (int rr = 0; rr < 4; ++rr) {
        int gr = rbase + rr;
        if (gr < NN) {
            float s = rs[gr];
#pragma unroll
            for (int nt = 0; nt < 8; ++nt)
                Cm[(size_t)gr * DD + nt * 16 + l16] = f2bf(acc[nt][rr] * s);
        }
    }
}

// ---- CSR aggregate, deep-ILP: per 16-neighbor tile, ALL 16 row-gathers are
// issued before any consumption (FMA weights mask the tail — dummy loads hit
// row 0, L1-resident). H[n] = bf16((sum T[s]) * r_in[n] + b). ----
#define ACC8(u, wk) \
    a0 += wk * bf2f(u.x & 0xffff); a1 += wk * bf2f(u.x >> 16); \
    a2 += wk * bf2f(u.y & 0xffff); a3 += wk * bf2f(u.y >> 16); \
    a4 += wk * bf2f(u.z & 0xffff); a5 += wk * bf2f(u.z >> 16); \
    a6 += wk * bf2f(u.w & 0xffff); a7 += wk * bf2f(u.w >> 16);

__global__ __launch_bounds__(256) void k_aggregate(const unsigned short* __restrict__ T,
                                                   const int* __restrict__ row_ptr,
                                                   const int* __restrict__ col,
                                                   const float* __restrict__ r_in,
                                                   const float* __restrict__ b,
                                                   unsigned short* __restrict__ H) {
    int wave = threadIdx.x >> 6, lane = threadIdx.x & 63;
    int sub = lane >> 4, l16 = lane & 15;
    int node = blockIdx.x * 16 + wave * 4 + sub;
    if (node >= NN) return;
    int beg = row_ptr[node], end = row_ptr[node + 1];
    float a0 = 0.f, a1 = 0.f, a2 = 0.f, a3 = 0.f, a4 = 0.f, a5 = 0.f, a6 = 0.f, a7 = 0.f;
    const unsigned short* Tl = T + l16 * 8;
    int grp = sub << 4;
    for (int base = beg; base < end; base += 16) {
        int m = end - base; if (m > 16) m = 16;
        int myidx = (l16 < m) ? col[base + l16] : 0;
        int s0  = __shfl(myidx, grp | 0),  s1  = __shfl(myidx, grp | 1);
        int s2  = __shfl(myidx, grp | 2),  s3  = __shfl(myidx, grp | 3);
        int s4  = __shfl(myidx, grp | 4),  s5  = __shfl(myidx, grp | 5);
        int s6  = __shfl(myidx, grp | 6),  s7  = __shfl(myidx, grp | 7);
        int s8  = __shfl(myidx, grp | 8),  s9  = __shfl(myidx, grp | 9);
        int s10 = __shfl(myidx, grp | 10), s11 = __shfl(myidx, grp | 11);
        int s12 = __shfl(myidx, grp | 12), s13 = __shfl(myidx, grp | 13);
        int s14 = __shfl(myidx, grp | 14), s15 = __shfl(myidx, grp | 15);
        uint4 u0  = *(const uint4*)(Tl + (size_t)s0  * DD);
        uint4 u1  = *(const uint4*)(Tl + (size_t)s1  * DD);
        uint4 u2  = *(const uint4*)(Tl + (size_t)s2  * DD);
        uint4 u3  = *(const uint4*)(Tl + (size_t)s3  * DD);
        uint4 u4  = *(const uint4*)(Tl + (size_t)s4  * DD);
        uint4 u5  = *(const uint4*)(Tl + (size_t)s5  * DD);
        uint4 u6  = *(const uint4*)(Tl + (size_t)s6  * DD);
        uint4 u7  = *(const uint4*)(Tl + (size_t)s7  * DD);
        uint4 u8  = *(const uint4*)(Tl + (size_t)s8  * DD);
        uint4 u9  = *(const uint4*)(Tl + (size_t)s9  * DD);
        uint4 u10 = *(const uint4*)(Tl + (size_t)s10 * DD);
        uint4 u11 = *(const uint4*)(Tl + (size_t)s11 * DD);
        uint4 u12 = *(const uint4*)(Tl + (size_t)s12 * DD);
        uint4 u13 = *(const uint4*)(Tl + (size_t)s13 * DD);
        uint4 u14 = *(const uint4*)(Tl + (size_t)s14 * DD);
        uint4 u15 = *(const uint4*)(Tl + (size_t)s15 * DD);
        float w0  = 0  < m ? 1.f : 0.f, w1  = 1  < m ? 1.f : 0.f;
        float w2  = 2  < m ? 1.f : 0.f, w3  = 3  < m ? 1.f : 0.f;
        float w4  = 4  < m ? 1.f : 0.f, w5  = 5  < m ? 1.f : 0.f;
        float w6  = 6  < m ? 1.f : 0.f, w7  = 7  < m ? 1.f : 0.f;
        float w8  = 8  < m ? 1.f : 0.f, w9  = 9  < m ? 1.f : 0.f;
        float w10 = 10 < m ? 1.f : 0.f, w11 = 11 < m ? 1.f : 0.f;
        float w12 = 12 < m ? 1.f : 0.f, w13 = 13 < m ? 1.f : 0.f;
        float w14 = 14 < m ? 1.f : 0.f, w15 = 15 < m ? 1.f : 0.f;
        ACC8(u0, w0)   ACC8(u1, w1)   ACC8(u2, w2)   ACC8(u3, w3)
        ACC8(u4, w4)   ACC8(u5, w5)   ACC8(u6, w6)   ACC8(u7, w7)
        ACC8(u8, w8)   ACC8(u9, w9)   ACC8(u10, w10) ACC8(u11, w11)
        ACC8(u12, w12) ACC8(u13, w13) ACC8(u14, w14) ACC8(u15, w15)
    }
    float rv = r_in[node];
    float4 bl = *(const float4*)(b + l16 * 8);
    float4 bh = *(const float4*)(b + l16 * 8 + 4);
    uint4 w;
    w.x = (unsigned int)f2bf(a0 * rv + bl.x) | ((unsigned int)f2bf(a1 * rv + bl.y) << 16);
    w.y = (unsigned int)f2bf(a2 * rv + bl.z) | ((unsigned int)f2bf(a3 * rv + bl.w) << 16);
    w.z = (unsigned int)f2bf(a4 * rv + bh.x) | ((unsigned int)f2bf(a5 * rv + bh.y) << 16);
    w.w = (unsigned int)f2bf(a6 * rv + bh.z) | ((unsigned int)f2bf(a7 * rv + bh.w) << 16);
    *(uint4*)(H + (size_t)node * DD + l16 * 8) = w;
}

// ---- MFMA MLP: P[n] = softmax(relu(h2[n]@dW + db)@oW + ob) ----
__global__ __launch_bounds__(256) void k_mlp_mfma(const unsigned short* __restrict__ H2,
                                                  const unsigned short* __restrict__ BTd,
                                                  const float* __restrict__ db,
                                                  const float* __restrict__ oW,
                                                  const float* __restrict__ ob,
                                                  float* __restrict__ P) {
    __shared__ unsigned short As[64][136];
    __shared__ unsigned short Bs[128][136];
    int tid = threadIdx.x, lane = tid & 63, wave = tid >> 6;
    int quad = lane >> 4, l16 = lane & 15;
    int row0 = blockIdx.x * 64;
#pragma unroll
    for (int p = 0; p < 4; ++p) {
        int fid = tid + p * 256;
        int rr = fid >> 4, c = fid & 15;
        int gr = row0 + rr; if (gr > NN - 1) gr = NN - 1;
        *(uint4*)&As[rr][c * 8] = *(const uint4*)(H2 + (size_t)gr * DD + c * 8);
    }
    short8 af[4];
    floatx4 acc[16];
#pragma unroll
    for (int i = 0; i < 16; ++i) acc[i] = (floatx4){0.f, 0.f, 0.f, 0.f};

    for (int ch = 0; ch < 2; ++ch) {
        __syncthreads();
#pragma unroll
        for (int p = 0; p < 8; ++p) {
            int fid = tid + p * 256;
            int rr = fid >> 4, c = fid & 15;
            *(uint4*)&Bs[rr][c * 8] = *(const uint4*)(BTd + (size_t)(ch * 128 + rr) * DD + c * 8);
        }
        __syncthreads();
        if (ch == 0) {
#pragma unroll
            for (int ks = 0; ks < 4; ++ks)
                af[ks] = *(const short8*)&As[wave * 16 + l16][ks * 32 + quad * 8];
        }
#pragma unroll
        for (int ks = 0; ks < 4; ++ks) {
#pragma unroll
            for (int nt = 0; nt < 8; ++nt) {
                short8 bf = *(const short8*)&Bs[nt * 16 + l16][ks * 32 + quad * 8];
                acc[ch * 8 + nt] =
                    __builtin_amdgcn_mfma_f32_16x16x32_bf16(af[ks], bf, acc[ch * 8 + nt], 0, 0, 0);
            }
        }
    }
    int rbase = row0 + wave * 16 + quad * 4;
#pragma unroll
    for (int rr = 0; rr < 4; ++rr) {
        float p0 = 0.f, p1 = 0.f;
#pragma unroll
        for (int ch = 0; ch < 2; ++ch) {
#pragma unroll
            for (int nt = 0; nt < 8; ++nt) {
                int colc = ch * 128 + nt * 16 + l16;
                float h = acc[ch * 8 + nt][rr] + db[colc];
                h = fmaxf(h, 0.f);
                p0 += h * oW[2 * colc];
                p1 += h * oW[2 * colc + 1];
            }
        }
#pragma unroll
        for (int m = 8; m >= 1; m >>= 1) {
            p0 += __shfl_xor(p0, m, 16);
            p1 += __shfl_xor(p1, m, 16);
        }
        if (l16 == 0) {
            int gr = rbase + rr;
            if (gr < NN) {
                float l0 = p0 + ob[0], l1 = p1 + ob[1];
                float mx = fmaxf(l0, l1);
                float e0 = __expf(l0 - mx), e1 = __expf(l1 - mx);
                float inv = 1.f / (e0 + e1);
                float2 pr = {e0 * inv, e1 * inv};
                *(float2*)(P + 2 * gr) = pr;
            }
        }
    }
}

// ---- final gather ----
__global__ void k_gather(const int* __restrict__ sidx, const int* __restrict__ oe,
                         const float* __restrict__ P, float* __restrict__ out) {
    int i = blockIdx.x * 256 + threadIdx.x;
    if (i >= NS) return;
    int node = oe[sidx[i]];
    float2 v = *(const float2*)(P + 2 * node);
    *(float2*)(out + 2 * i) = v;
}

extern "C" void kernel_launch(void* const* d_in, const int* in_sizes, int n_in,
                              void* d_out, int out_size, void* d_ws, size_t ws_size,
                              hipStream_t stream) {
    const float* node_state = (const float*)d_in[0];
    const int* ei   = (const int*)d_in[1];
    const int* oe   = (const int*)d_in[2];
    const int* sidx = (const int*)d_in[3];
    const float* W1 = (const float*)d_in[4];
    const float* b1 = (const float*)d_in[5];
    const float* W2 = (const float*)d_in[6];
    const float* b2 = (const float*)d_in[7];
    const float* dW = (const float*)d_in[8];
    const float* db = (const float*)d_in[9];
    const float* oW = (const float*)d_in[10];
    const float* ob = (const float*)d_in[11];
    float* out = (float*)d_out;

    char* ws = (char*)d_ws;
    size_t off = 0;
    auto carve = [&](size_t bytes) -> char* {
        char* p = ws + off;
        off = (off + bytes + 255) & ~(size_t)255;
        return p;
    };
    float* r       = (float*)carve((size_t)2 * NN * 4);
    int*   row_ptr = (int*)carve((size_t)(NN + 1) * 4);
    int*   cur     = (int*)carve((size_t)NN * 4);
    int*   col     = (int*)carve((size_t)NE * 4);
    int*   deg     = (int*)carve((size_t)2 * NN * 4);
    unsigned long long* status = (unsigned long long*)carve(64 * 8);
    unsigned short* t   = (unsigned short*)carve((size_t)NN * DD * 2);
    unsigned short* h   = (unsigned short*)carve((size_t)NN * DD * 2);
    unsigned short* BT1 = (unsigned short*)carve((size_t)DD * DD * 2);
    unsigned short* BT2 = (unsigned short*)carve((size_t)DD * DD * 2);
    unsigned short* BTd = (unsigned short*)carve((size_t)DD * NU * 2);
    float* P = (float*)t;   // alias: t dead after second aggregate

    float* r_out = r;
    float* r_in  = r + NN;

    // CSR build via global atomics (L2-resolved): zero -> degree -> scan -> bucket
    k_prep<<<98, 256, 0, stream>>>(deg, status);
    k_deg<<<1172, 256, 0, stream>>>(ei, deg);
    k_scan<<<NSCAN, 256, 0, stream>>>(deg, r, row_ptr, cur, status,
                                      W1, W2, dW, BT1, BT2, BTd);

    // bucket (atomic cursors) + layer-1 GEMM in one wide kernel
    k_gemm1_bucket<<<BBK + NB64, 256, 0, stream>>>(node_state, r_out, BT1, t,
                                                   ei, cur, col);
    k_aggregate<<<(NN + 15) / 16, 256, 0, stream>>>(t, row_ptr, col, r_in, b1, h);

    // layer 2
    k_gemm_bf<<<NB64, 256, 0, stream>>>(h, r_out, BT2, t);
    k_aggregate<<<(NN + 15) / 16, 256, 0, stream>>>(t, row_ptr, col, r_in, b2, h);

    // per-node MLP + softmax, then gather
    k_mlp_mfma<<<NB64, 256, 0, stream>>>(h, BTd, db, oW, ob, P);
    k_gather<<<(NS + 255) / 256, 256, 0, stream>>>(sidx, oe, P, out);
}

// Round 4
// 230.403 us; speedup vs baseline: 1.1688x; 1.1688x over previous
//
#include <hip/hip_runtime.h>

#define NN 50000
#define DD 128
#define NE 600000
#define NP 200000
#define NS 300000
#define NU 256
#define NBH 64      // histogram/bucket blocks per half
#define EPB 9375    // NE/NBH
#define NW 12500    // NN/4 byte-packed words
#define NB64 782    // ceil(NN/64)
#define NSCAN 49    // ceil(NW/256) blocks own the row_ptr scan

typedef __attribute__((ext_vector_type(8))) short short8;
typedef __attribute__((ext_vector_type(4))) float floatx4;

__device__ inline float bf2f(unsigned int u16) {
    unsigned int x = u16 << 16;
    float f; __builtin_memcpy(&f, &x, 4); return f;
}
__device__ inline unsigned short f2bf(float f) {
    unsigned int x; __builtin_memcpy(&x, &f, 4);
    unsigned int lsb = (x >> 16) & 1u;
    x += 0x7fffu + lsb;
    return (unsigned short)(x >> 16);
}

// ---- per-block byte histograms: grid (NBH, 2); y=0 counts src, y=1 counts dst ----
// 512 threads; absorbs the weight bf16 transpose-cast (gid covers 65536 exactly)
// and zeroes the lookback status array (consumed by k_mid, stream-ordered).
__global__ __launch_bounds__(512) void k_hist(const int* __restrict__ ei,
                                              unsigned int* __restrict__ P,
                                              unsigned long long* __restrict__ status,
                                              const float* __restrict__ W1,
                                              const float* __restrict__ W2,
                                              const float* __restrict__ dW,
                                              unsigned short* __restrict__ BT1,
                                              unsigned short* __restrict__ BT2,
                                              unsigned short* __restrict__ BTd) {
    __shared__ unsigned int hw[NW];
    int b = blockIdx.x, half = blockIdx.y, tid = threadIdx.x;
    if (b == 0 && half == 0 && tid < 64) status[tid] = 0ull;
    for (int w = tid; w < NW; w += 512) hw[w] = 0;
    {   // weight transpose + bf16 cast: 128 blocks x 512 = 65536 elements, 1 each
        int gid = (half * NBH + b) * 512 + tid;
        if (gid < 16384) { int rr = gid >> 7, cc = gid & 127; BT1[cc * 128 + rr] = f2bf(W1[gid]); }
        else if (gid < 32768) { int t2 = gid - 16384; int rr = t2 >> 7, cc = t2 & 127; BT2[cc * 128 + rr] = f2bf(W2[t2]); }
        else { int t2 = gid - 32768; int rr = t2 >> 8, cc = t2 & 255; BTd[cc * 128 + rr] = f2bf(dW[t2]); }
    }
    __syncthreads();
    const int* src = ei + (size_t)half * NE;
    int e0 = b * EPB, e1 = min(e0 + EPB, NE);
    for (int e = e0 + tid; e < e1; e += 512) {
        int s = src[e];
        atomicAdd(&hw[s >> 2], 1u << ((s & 3) * 8));
    }
    __syncthreads();
    unsigned int* Pb = P + ((size_t)half * NBH + b) * NW;
    for (int w = tid; w < NW; w += 512) Pb[w] = hw[w];
}

// ---- fused mid-chain, one dispatch, grid = 2*NSCAN + 64 = 162:
//  blocks 0..48   : dst-half column reduce (64-deep) writing baseb prefix bytes
//                   inline, r_in, then row_ptr scan w/ wave-parallel lookback
//  blocks 49..97  : src-half column reduce -> r_out
//  blocks 98..161 : (none; weight cast moved into k_hist) -- kept small spill of
//                   nothing, grid is simply 98.
__global__ __launch_bounds__(256) void k_mid(
    const unsigned int* __restrict__ P_hist, float* __restrict__ r,
    int* __restrict__ row_ptr, unsigned char* __restrict__ baseb,
    unsigned long long* __restrict__ status)
{
    int b = blockIdx.x, tid = threadIdx.x, lane = tid & 63, w = tid >> 6;

    if (b < NSCAN) {
        int gid = b * 256 + tid;
        int4 v = {0, 0, 0, 0};
        if (gid < NW) {   // dst half: reduce + emit baseb prefixes inline
            const unsigned int* Ph = P_hist + (size_t)NBH * NW + gid;
            int c0 = 0, c1 = 0, c2 = 0, c3 = 0;
            unsigned char* bb = baseb + gid * 4;
            for (int b2 = 0; b2 < NBH; ++b2) {
                unsigned int x = Ph[(size_t)b2 * NW];
                uchar4 pb = {(unsigned char)c0, (unsigned char)c1,
                             (unsigned char)c2, (unsigned char)c3};
                *(uchar4*)(bb + (size_t)b2 * NN) = pb;
                c0 += x & 0xff; c1 += (x >> 8) & 0xff;
                c2 += (x >> 16) & 0xff; c3 += x >> 24;
            }
            v = (int4){c0, c1, c2, c3};
            float4 rr = {rsqrtf((float)max(c0, 1)), rsqrtf((float)max(c1, 1)),
                         rsqrtf((float)max(c2, 1)), rsqrtf((float)max(c3, 1))};
            *(float4*)(r + NN + gid * 4) = rr;
        }

        // block-local scan + wave-parallel decoupled lookback (49 co-resident)
        __shared__ int wsum[4];
        __shared__ long long sbase;
        int tot = v.x + v.y + v.z + v.w;
        int x = tot;
#pragma unroll
        for (int off = 1; off < 64; off <<= 1) {
            int y = __shfl_up(x, off);
            if (lane >= off) x += y;
        }
        if (lane == 63) wsum[w] = x;
        __syncthreads();
        int woff = 0;
#pragma unroll
        for (int i = 0; i < 4; ++i) if (i < w) woff += wsum[i];
        if (w == 0) {
            int btot = wsum[0] + wsum[1] + wsum[2] + wsum[3];
            if (lane == 0) {
                __threadfence();
                atomicExch(&status[b], (1ull << 62) | (unsigned long long)btot);
            }
            long long run = 0;
            if (lane < b) {
                unsigned long long s;
                do { s = atomicAdd(&status[lane], 0ull); } while (s == 0ull);
                run = (long long)(s & 0x3fffffffffffffffull);
            }
#pragma unroll
            for (int off = 32; off > 0; off >>= 1) run += __shfl_down(run, off);
            if (lane == 0) sbase = run;
        }
        __syncthreads();
        if (gid < NW) {
            int base = (int)sbase + woff + (x - tot);
            int4 o = {base, base + v.x, base + v.x + v.y, base + v.x + v.y + v.z};
            *(int4*)(row_ptr + gid * 4) = o;
        }
        if (b == 0 && tid == 0) row_ptr[NN] = NE;
    } else {
        int wl = (b - NSCAN) * 256 + tid;
        if (wl < NW) {   // src half: reduce -> r_out
            const unsigned int* Ph = P_hist + wl;
            int c0 = 0, c1 = 0, c2 = 0, c3 = 0;
            for (int b2 = 0; b2 < NBH; ++b2) {
                unsigned int x = Ph[(size_t)b2 * NW];
                c0 += x & 0xff; c1 += (x >> 8) & 0xff;
                c2 += (x >> 16) & 0xff; c3 += x >> 24;
            }
            float4 rr = {rsqrtf((float)max(c0, 1)), rsqrtf((float)max(c1, 1)),
                         rsqrtf((float)max(c2, 1)), rsqrtf((float)max(c3, 1))};
            *(float4*)(r + wl * 4) = rr;
        }
    }
}

// ---- wide kernel: blocks 0..NBH-1 bucket edges; blocks NBH.. do layer-1 GEMM ----
// Both depend only on k_mid; merging lets the short GEMM hide under the bucket.
__global__ __launch_bounds__(256) void k_gemm1_bucket(
    const float* __restrict__ A, const float* __restrict__ rs,
    const unsigned short* __restrict__ BT, unsigned short* __restrict__ Cm,
    const int* __restrict__ ei, const int* __restrict__ row_ptr,
    const unsigned char* __restrict__ baseb, int* __restrict__ col)
{
    __shared__ unsigned short sm[26112];   // 52224 B: GEMM tiles / bucket cursors (union)
    int b = blockIdx.x, tid = threadIdx.x;

    if (b < NBH) {
        // ---- bucket role ----
        unsigned int* cw = (unsigned int*)sm;
        for (int w = tid; w < NW; w += 256) cw[w] = 0;
        __syncthreads();
        const unsigned char* bt = baseb + (size_t)b * NN;
        int e0 = b * EPB, e1 = min(e0 + EPB, NE);
        for (int e = e0 + tid; e < e1; e += 256) {
            int s = ei[e], d = ei[NE + e];
            int sh = (d & 3) * 8;
            unsigned int old = atomicAdd(&cw[d >> 2], 1u << sh);
            col[row_ptr[d] + (int)bt[d] + ((old >> sh) & 0xff)] = s;
        }
        return;
    }

    // ---- GEMM role: t = (bf16(A_f32) @ W1) * r_out ----
    unsigned short (*As)[136] = (unsigned short(*)[136])sm;
    unsigned short (*Bs)[136] = (unsigned short(*)[136])(sm + 64 * 136);
    int lane = tid & 63, wave = tid >> 6;
    int quad = lane >> 4, l16 = lane & 15;
    int row0 = (b - NBH) * 64;

#pragma unroll
    for (int p = 0; p < 8; ++p) {
        int fid = tid + p * 256;
        int rr = fid >> 5, c = fid & 31;
        int gr = row0 + rr; if (gr > NN - 1) gr = NN - 1;
        float4 v = *(const float4*)(A + (size_t)gr * DD + c * 4);
        ushort4 u;
        u.x = f2bf(v.x); u.y = f2bf(v.y); u.z = f2bf(v.z); u.w = f2bf(v.w);
        *(ushort4*)&As[rr][c * 4] = u;
    }
#pragma unroll
    for (int p = 0; p < 8; ++p) {
        int fid = tid + p * 256;
        int rr = fid >> 4, c = fid & 15;
        *(uint4*)&Bs[rr][c * 8] = *(const uint4*)(BT + (size_t)rr * DD + c * 8);
    }
    __syncthreads();

    short8 af[4];
#pragma unroll
    for (int ks = 0; ks < 4; ++ks)
        af[ks] = *(const short8*)&As[wave * 16 + l16][ks * 32 + quad * 8];
    floatx4 acc[8];
#pragma unroll
    for (int nt = 0; nt < 8; ++nt) acc[nt] = (floatx4){0.f, 0.f, 0.f, 0.f};
#pragma unroll
    for (int ks = 0; ks < 4; ++ks) {
#pragma unroll
        for (int nt = 0; nt < 8; ++nt) {
            short8 bf = *(const short8*)&Bs[nt * 16 + l16][ks * 32 + quad * 8];
            acc[nt] = __builtin_amdgcn_mfma_f32_16x16x32_bf16(af[ks], bf, acc[nt], 0, 0, 0);
        }
    }
    int rbase = row0 + wave * 16 + quad * 4;
#pragma unroll
    for (int rr = 0; rr < 4; ++rr) {
        int gr = rbase + rr;
        if (gr < NN) {
            float s = rs[gr];
#pragma unroll
            for (int nt = 0; nt < 8; ++nt)
                Cm[(size_t)gr * DD + nt * 16 + l16] = f2bf(acc[nt][rr] * s);
        }
    }
}

// ---- MFMA GEMM (layer 2): Cm = rowscale(A_bf16 @ W2) ----
__global__ __launch_bounds__(256) void k_gemm_bf(const unsigned short* __restrict__ A,
                                                 const float* __restrict__ rs,
                                                 const unsigned short* __restrict__ BT,
                                                 unsigned short* __restrict__ Cm) {
    __shared__ unsigned short As[64][136];
    __shared__ unsigned short Bs[128][136];
    int tid = threadIdx.x, lane = tid & 63, wave = tid >> 6;
    int quad = lane >> 4, l16 = lane & 15;
    int row0 = blockIdx.x * 64;

#pragma unroll
    for (int p = 0; p < 4; ++p) {
        int fid = tid + p * 256;
        int rr = fid >> 4, c = fid & 15;
        int gr = row0 + rr; if (gr > NN - 1) gr = NN - 1;
        *(uint4*)&As[rr][c * 8] = *(const uint4*)(A + (size_t)gr * DD + c * 8);
    }
#pragma unroll
    for (int p = 0; p < 8; ++p) {
        int fid = tid + p * 256;
        int rr = fid >> 4, c = fid & 15;
        *(uint4*)&Bs[rr][c * 8] = *(const uint4*)(BT + (size_t)rr * DD + c * 8);
    }
    __syncthreads();

    short8 af[4];
#pragma unroll
    for (int ks = 0; ks < 4; ++ks)
        af[ks] = *(const short8*)&As[wave * 16 + l16][ks * 32 + quad * 8];
    floatx4 acc[8];
#pragma unroll
    for (int nt = 0; nt < 8; ++nt) acc[nt] = (floatx4){0.f, 0.f, 0.f, 0.f};
#pragma unroll
    for (int ks = 0; ks < 4; ++ks) {
#pragma unroll
        for (int nt = 0; nt < 8; ++nt) {
            short8 bf = *(const short8*)&Bs[nt * 16 + l16][ks * 32 + quad * 8];
            acc[nt] = __builtin_amdgcn_mfma_f32_16x16x32_bf16(af[ks], bf, acc[nt], 0, 0, 0);
        }
    }
    int rbase = row0 + wave * 16 + quad * 4;
#pragma unroll
    for (int rr = 0; rr < 4; ++rr) {
        int gr = rbase + rr;
        if (gr < NN) {
            float s = rs[gr];
#pragma unroll
            for (int nt = 0; nt < 8; ++nt)
                Cm[(size_t)gr * DD + nt * 16 + l16] = f2bf(acc[nt][rr] * s);
        }
    }
}

// ---- CSR aggregate + fused finalize: H[n] = bf16((sum T[s]) * r_in[n] + b) ----
// 16 lanes/node, uint4/lane; 4 gathers in flight. launch_bounds(256,6): cap
// VGPR at 85 -> 6 waves/SIMD for latency hiding (body needs ~50, no spill).
__global__ __launch_bounds__(256, 6) void k_aggregate(const unsigned short* __restrict__ T,
                                                      const int* __restrict__ row_ptr,
                                                      const int* __restrict__ col,
                                                      const float* __restrict__ r_in,
                                                      const float* __restrict__ b,
                                                      unsigned short* __restrict__ H) {
    int wave = threadIdx.x >> 6, lane = threadIdx.x & 63;
    int sub = lane >> 4, l16 = lane & 15;
    int node = blockIdx.x * 16 + wave * 4 + sub;
    if (node >= NN) return;
    int beg = row_ptr[node], end = row_ptr[node + 1];
    float a0 = 0.f, a1 = 0.f, a2 = 0.f, a3 = 0.f, a4 = 0.f, a5 = 0.f, a6 = 0.f, a7 = 0.f;
    for (int base = beg; base < end; base += 16) {
        int m = end - base; if (m > 16) m = 16;
        int myidx = (l16 < m) ? col[base + l16] : 0;
        int j = 0;
        for (; j + 4 <= m; j += 4) {
            int s0 = __shfl(myidx, (sub << 4) | j);
            int s1 = __shfl(myidx, (sub << 4) | (j + 1));
            int s2 = __shfl(myidx, (sub << 4) | (j + 2));
            int s3 = __shfl(myidx, (sub << 4) | (j + 3));
            uint4 v0 = *(const uint4*)(T + (size_t)s0 * DD + l16 * 8);
            uint4 v1 = *(const uint4*)(T + (size_t)s1 * DD + l16 * 8);
            uint4 v2 = *(const uint4*)(T + (size_t)s2 * DD + l16 * 8);
            uint4 v3 = *(const uint4*)(T + (size_t)s3 * DD + l16 * 8);
            a0 += bf2f(v0.x & 0xffff) + bf2f(v1.x & 0xffff) + bf2f(v2.x & 0xffff) + bf2f(v3.x & 0xffff);
            a1 += bf2f(v0.x >> 16)    + bf2f(v1.x >> 16)    + bf2f(v2.x >> 16)    + bf2f(v3.x >> 16);
            a2 += bf2f(v0.y & 0xffff) + bf2f(v1.y & 0xffff) + bf2f(v2.y & 0xffff) + bf2f(v3.y & 0xffff);
            a3 += bf2f(v0.y >> 16)    + bf2f(v1.y >> 16)    + bf2f(v2.y >> 16)    + bf2f(v3.y >> 16);
            a4 += bf2f(v0.z & 0xffff) + bf2f(v1.z & 0xffff) + bf2f(v2.z & 0xffff) + bf2f(v3.z & 0xffff);
            a5 += bf2f(v0.z >> 16)    + bf2f(v1.z >> 16)    + bf2f(v2.z >> 16)    + bf2f(v3.z >> 16);
            a6 += bf2f(v0.w & 0xffff) + bf2f(v1.w & 0xffff) + bf2f(v2.w & 0xffff) + bf2f(v3.w & 0xffff);
            a7 += bf2f(v0.w >> 16)    + bf2f(v1.w >> 16)    + bf2f(v2.w >> 16)    + bf2f(v3.w >> 16);
        }
        for (; j < m; ++j) {
            int s0 = __shfl(myidx, (sub << 4) | j);
            uint4 v0 = *(const uint4*)(T + (size_t)s0 * DD + l16 * 8);
            a0 += bf2f(v0.x & 0xffff); a1 += bf2f(v0.x >> 16);
            a2 += bf2f(v0.y & 0xffff); a3 += bf2f(v0.y >> 16);
            a4 += bf2f(v0.z & 0xffff); a5 += bf2f(v0.z >> 16);
            a6 += bf2f(v0.w & 0xffff); a7 += bf2f(v0.w >> 16);
        }
    }
    float rv = r_in[node];
    float4 bl = *(const float4*)(b + l16 * 8);
    float4 bh = *(const float4*)(b + l16 * 8 + 4);
    uint4 w;
    w.x = (unsigned int)f2bf(a0 * rv + bl.x) | ((unsigned int)f2bf(a1 * rv + bl.y) << 16);
    w.y = (unsigned int)f2bf(a2 * rv + bl.z) | ((unsigned int)f2bf(a3 * rv + bl.w) << 16);
    w.z = (unsigned int)f2bf(a4 * rv + bh.x) | ((unsigned int)f2bf(a5 * rv + bh.y) << 16);
    w.w = (unsigned int)f2bf(a6 * rv + bh.z) | ((unsigned int)f2bf(a7 * rv + bh.w) << 16);
    *(uint4*)(H + (size_t)node * DD + l16 * 8) = w;
}

// ---- MFMA MLP: P[n] = softmax(relu(h2[n]@dW + db)@oW + ob) ----
__global__ __launch_bounds__(256) void k_mlp_mfma(const unsigned short* __restrict__ H2,
                                                  const unsigned short* __restrict__ BTd,
                                                  const float* __restrict__ db,
                                                  const float* __restrict__ oW,
                                                  const float* __restrict__ ob,
                                                  float* __restrict__ P) {
    __shared__ unsigned short As[64][136];
    __shared__ unsigned short Bs[128][136];
    int tid = threadIdx.x, lane = tid & 63, wave = tid >> 6;
    int quad = lane >> 4, l16 = lane & 15;
    int row0 = blockIdx.x * 64;
#pragma unroll
    for (int p = 0; p < 4; ++p) {
        int fid = tid + p * 256;
        int rr = fid >> 4, c = fid & 15;
        int gr = row0 + rr; if (gr > NN - 1) gr = NN - 1;
        *(uint4*)&As[rr][c * 8] = *(const uint4*)(H2 + (size_t)gr * DD + c * 8);
    }
    short8 af[4];
    floatx4 acc[16];
#pragma unroll
    for (int i = 0; i < 16; ++i) acc[i] = (floatx4){0.f, 0.f, 0.f, 0.f};

    for (int ch = 0; ch < 2; ++ch) {
        __syncthreads();
#pragma unroll
        for (int p = 0; p < 8; ++p) {
            int fid = tid + p * 256;
            int rr = fid >> 4, c = fid & 15;
            *(uint4*)&Bs[rr][c * 8] = *(const uint4*)(BTd + (size_t)(ch * 128 + rr) * DD + c * 8);
        }
        __syncthreads();
        if (ch == 0) {
#pragma unroll
            for (int ks = 0; ks < 4; ++ks)
                af[ks] = *(const short8*)&As[wave * 16 + l16][ks * 32 + quad * 8];
        }
#pragma unroll
        for (int ks = 0; ks < 4; ++ks) {
#pragma unroll
            for (int nt = 0; nt < 8; ++nt) {
                short8 bf = *(const short8*)&Bs[nt * 16 + l16][ks * 32 + quad * 8];
                acc[ch * 8 + nt] =
                    __builtin_amdgcn_mfma_f32_16x16x32_bf16(af[ks], bf, acc[ch * 8 + nt], 0, 0, 0);
            }
        }
    }
    int rbase = row0 + wave * 16 + quad * 4;
#pragma unroll
    for (int rr = 0; rr < 4; ++rr) {
        float p0 = 0.f, p1 = 0.f;
#pragma unroll
        for (int ch = 0; ch < 2; ++ch) {
#pragma unroll
            for (int nt = 0; nt < 8; ++nt) {
                int colc = ch * 128 + nt * 16 + l16;
                float h = acc[ch * 8 + nt][rr] + db[colc];
                h = fmaxf(h, 0.f);
                p0 += h * oW[2 * colc];
                p1 += h * oW[2 * colc + 1];
            }
        }
#pragma unroll
        for (int m = 8; m >= 1; m >>= 1) {
            p0 += __shfl_xor(p0, m, 16);
            p1 += __shfl_xor(p1, m, 16);
        }
        if (l16 == 0) {
            int gr = rbase + rr;
            if (gr < NN) {
                float l0 = p0 + ob[0], l1 = p1 + ob[1];
                float mx = fmaxf(l0, l1);
                float e0 = __expf(l0 - mx), e1 = __expf(l1 - mx);
                float inv = 1.f / (e0 + e1);
                float2 pr = {e0 * inv, e1 * inv};
                *(float2*)(P + 2 * gr) = pr;
            }
        }
    }
}

// ---- final gather ----
__global__ void k_gather(const int* __restrict__ sidx, const int* __restrict__ oe,
                         const float* __restrict__ P, float* __restrict__ out) {
    int i = blockIdx.x * 256 + threadIdx.x;
    if (i >= NS) return;
    int node = oe[sidx[i]];
    float2 v = *(const float2*)(P + 2 * node);
    *(float2*)(out + 2 * i) = v;
}

extern "C" void kernel_launch(void* const* d_in, const int* in_sizes, int n_in,
                              void* d_out, int out_size, void* d_ws, size_t ws_size,
                              hipStream_t stream) {
    const float* node_state = (const float*)d_in[0];
    const int* ei   = (const int*)d_in[1];
    const int* oe   = (const int*)d_in[2];
    const int* sidx = (const int*)d_in[3];
    const float* W1 = (const float*)d_in[4];
    const float* b1 = (const float*)d_in[5];
    const float* W2 = (const float*)d_in[6];
    const float* b2 = (const float*)d_in[7];
    const float* dW = (const float*)d_in[8];
    const float* db = (const float*)d_in[9];
    const float* oW = (const float*)d_in[10];
    const float* ob = (const float*)d_in[11];
    float* out = (float*)d_out;

    char* ws = (char*)d_ws;
    size_t off = 0;
    auto carve = [&](size_t bytes) -> char* {
        char* p = ws + off;
        off = (off + bytes + 255) & ~(size_t)255;
        return p;
    };
    float* r       = (float*)carve((size_t)2 * NN * 4);
    int*   row_ptr = (int*)carve((size_t)(NN + 1) * 4);
    int*   col     = (int*)carve((size_t)NE * 4);
    unsigned int* P_hist = (unsigned int*)carve((size_t)2 * NBH * NW * 4);
    unsigned char* baseb = (unsigned char*)carve((size_t)NBH * NN);
    unsigned long long* status = (unsigned long long*)carve(64 * 8);
    unsigned short* t   = (unsigned short*)carve((size_t)NN * DD * 2);
    unsigned short* h   = (unsigned short*)carve((size_t)NN * DD * 2);
    unsigned short* BT1 = (unsigned short*)carve((size_t)DD * DD * 2);
    unsigned short* BT2 = (unsigned short*)carve((size_t)DD * DD * 2);
    unsigned short* BTd = (unsigned short*)carve((size_t)DD * NU * 2);
    float* P = (float*)t;   // alias: t dead after second aggregate

    float* r_out = r;
    float* r_in  = r + NN;

    // CSR build — no global atomics; weight cast folded into k_hist;
    // baseb emitted inline during k_mid's column reduce (no phase-D pass)
    k_hist<<<dim3(NBH, 2), 512, 0, stream>>>(ei, P_hist, status, W1, W2, dW,
                                             BT1, BT2, BTd);
    k_mid<<<2 * NSCAN, 256, 0, stream>>>(P_hist, r, row_ptr, baseb, status);

    // bucket + layer-1 GEMM in one wide kernel (independent given k_mid)
    k_gemm1_bucket<<<NBH + NB64, 256, 0, stream>>>(node_state, r_out, BT1, t,
                                                   ei, row_ptr, baseb, col);
    k_aggregate<<<(NN + 15) / 16, 256, 0, stream>>>(t, row_ptr, col, r_in, b1, h);

    // layer 2
    k_gemm_bf<<<NB64, 256, 0, stream>>>(h, r_out, BT2, t);
    k_aggregate<<<(NN + 15) / 16, 256, 0, stream>>>(t, row_ptr, col, r_in, b2, h);

    // per-node MLP + softmax, then gather
    k_mlp_mfma<<<NB64, 256, 0, stream>>>(h, BTd, db, oW, ob, P);
    k_gather<<<(NS + 255) / 256, 256, 0, stream>>>(sidx, oe, P, out);
}

// Round 5
// 225.888 us; speedup vs baseline: 1.1922x; 1.0200x over previous
//
#include <hip/hip_runtime.h>

#define NN 50000
#define DD 128
#define NE 600000
#define NP 200000
#define NS 300000
#define NU 256
#define NBH 128     // histogram/bucket blocks per half
#define EPB 4688    // NE/NBH (multiple of 4)
#define NW 12500    // NN/4 byte-packed words
#define NB64 782    // ceil(NN/64)
#define NSCAN 49    // ceil(NW/256) blocks own the row_ptr scan

typedef __attribute__((ext_vector_type(8))) short short8;
typedef __attribute__((ext_vector_type(4))) float floatx4;

__device__ inline float bf2f(unsigned int u16) {
    unsigned int x = u16 << 16;
    float f; __builtin_memcpy(&f, &x, 4); return f;
}
__device__ inline unsigned short f2bf(float f) {
    unsigned int x; __builtin_memcpy(&x, &f, 4);
    unsigned int lsb = (x >> 16) & 1u;
    x += 0x7fffu + lsb;
    return (unsigned short)(x >> 16);
}

// ---- per-block byte histograms: grid (NBH, 2); y=0 counts src, y=1 counts dst ----
// 512 threads; int4 edge loads; absorbs the weight bf16 transpose-cast and zeroes
// the lookback status array (consumed by k_mid, stream-ordered).
__global__ __launch_bounds__(512) void k_hist(const int* __restrict__ ei,
                                              unsigned int* __restrict__ P,
                                              unsigned long long* __restrict__ status,
                                              const float* __restrict__ W1,
                                              const float* __restrict__ W2,
                                              const float* __restrict__ dW,
                                              unsigned short* __restrict__ BT1,
                                              unsigned short* __restrict__ BT2,
                                              unsigned short* __restrict__ BTd) {
    __shared__ unsigned int hw[NW];
    int b = blockIdx.x, half = blockIdx.y, tid = threadIdx.x;
    if (b == 0 && half == 0 && tid < 64) status[tid] = 0ull;
    for (int w = tid; w < NW; w += 512) hw[w] = 0;
    {   // weight transpose + bf16 cast: 65536 elements over first 128 gid-blocks
        int gid = (half * NBH + b) * 512 + tid;
        if (gid < 16384) { int rr = gid >> 7, cc = gid & 127; BT1[cc * 128 + rr] = f2bf(W1[gid]); }
        else if (gid < 32768) { int t2 = gid - 16384; int rr = t2 >> 7, cc = t2 & 127; BT2[cc * 128 + rr] = f2bf(W2[t2]); }
        else if (gid < 65536) { int t2 = gid - 32768; int rr = t2 >> 8, cc = t2 & 255; BTd[cc * 128 + rr] = f2bf(dW[t2]); }
    }
    __syncthreads();
    const int* src = ei + (size_t)half * NE;
    int w0 = b * (EPB / 4), w1 = min(w0 + EPB / 4, NE / 4);
    for (int w = w0 + tid; w < w1; w += 512) {
        int4 e = ((const int4*)src)[w];
        atomicAdd(&hw[e.x >> 2], 1u << ((e.x & 3) * 8));
        atomicAdd(&hw[e.y >> 2], 1u << ((e.y & 3) * 8));
        atomicAdd(&hw[e.z >> 2], 1u << ((e.z & 3) * 8));
        atomicAdd(&hw[e.w >> 2], 1u << ((e.w & 3) * 8));
    }
    __syncthreads();
    unsigned int* Pb = P + ((size_t)half * NBH + b) * NW;
    for (int w = tid; w < NW; w += 512) Pb[w] = hw[w];
}

// ---- fused mid-chain, one dispatch, grid = 2*NSCAN = 98:
//  blocks 0..48  : dst-half column reduce (128-deep) emitting baseb prefix bytes
//                  inline, r_in, then row_ptr scan w/ wave-parallel lookback
//  blocks 49..97 : src-half column reduce -> r_out
__global__ __launch_bounds__(256) void k_mid(
    const unsigned int* __restrict__ P_hist, float* __restrict__ r,
    int* __restrict__ row_ptr, unsigned char* __restrict__ baseb,
    unsigned long long* __restrict__ status)
{
    int b = blockIdx.x, tid = threadIdx.x, lane = tid & 63, w = tid >> 6;

    if (b < NSCAN) {
        int gid = b * 256 + tid;
        int4 v = {0, 0, 0, 0};
        if (gid < NW) {   // dst half: reduce + emit baseb prefixes inline
            const unsigned int* Ph = P_hist + (size_t)NBH * NW + gid;
            int c0 = 0, c1 = 0, c2 = 0, c3 = 0;
            unsigned char* bb = baseb + gid * 4;
            for (int b2 = 0; b2 < NBH; ++b2) {
                unsigned int x = Ph[(size_t)b2 * NW];
                uchar4 pb = {(unsigned char)c0, (unsigned char)c1,
                             (unsigned char)c2, (unsigned char)c3};
                *(uchar4*)(bb + (size_t)b2 * NN) = pb;
                c0 += x & 0xff; c1 += (x >> 8) & 0xff;
                c2 += (x >> 16) & 0xff; c3 += x >> 24;
            }
            v = (int4){c0, c1, c2, c3};
            float4 rr = {rsqrtf((float)max(c0, 1)), rsqrtf((float)max(c1, 1)),
                         rsqrtf((float)max(c2, 1)), rsqrtf((float)max(c3, 1))};
            *(float4*)(r + NN + gid * 4) = rr;
        }

        // block-local scan + wave-parallel decoupled lookback (49 co-resident)
        __shared__ int wsum[4];
        __shared__ long long sbase;
        int tot = v.x + v.y + v.z + v.w;
        int x = tot;
#pragma unroll
        for (int off = 1; off < 64; off <<= 1) {
            int y = __shfl_up(x, off);
            if (lane >= off) x += y;
        }
        if (lane == 63) wsum[w] = x;
        __syncthreads();
        int woff = 0;
#pragma unroll
        for (int i = 0; i < 4; ++i) if (i < w) woff += wsum[i];
        if (w == 0) {
            int btot = wsum[0] + wsum[1] + wsum[2] + wsum[3];
            if (lane == 0) {
                __threadfence();
                atomicExch(&status[b], (1ull << 62) | (unsigned long long)btot);
            }
            long long run = 0;
            if (lane < b) {
                unsigned long long s;
                do { s = atomicAdd(&status[lane], 0ull); } while (s == 0ull);
                run = (long long)(s & 0x3fffffffffffffffull);
            }
#pragma unroll
            for (int off = 32; off > 0; off >>= 1) run += __shfl_down(run, off);
            if (lane == 0) sbase = run;
        }
        __syncthreads();
        if (gid < NW) {
            int base = (int)sbase + woff + (x - tot);
            int4 o = {base, base + v.x, base + v.x + v.y, base + v.x + v.y + v.z};
            *(int4*)(row_ptr + gid * 4) = o;
        }
        if (b == 0 && tid == 0) row_ptr[NN] = NE;
    } else {
        int wl = (b - NSCAN) * 256 + tid;
        if (wl < NW) {   // src half: reduce -> r_out
            const unsigned int* Ph = P_hist + wl;
            int c0 = 0, c1 = 0, c2 = 0, c3 = 0;
            for (int b2 = 0; b2 < NBH; ++b2) {
                unsigned int x = Ph[(size_t)b2 * NW];
                c0 += x & 0xff; c1 += (x >> 8) & 0xff;
                c2 += (x >> 16) & 0xff; c3 += x >> 24;
            }
            float4 rr = {rsqrtf((float)max(c0, 1)), rsqrtf((float)max(c1, 1)),
                         rsqrtf((float)max(c2, 1)), rsqrtf((float)max(c3, 1))};
            *(float4*)(r + wl * 4) = rr;
        }
    }
}

// ---- wide kernel: blocks 0..NBH-1 bucket edges; blocks NBH.. do layer-1 GEMM ----
// Both depend only on k_mid; merging lets the short GEMM hide under the bucket.
__global__ __launch_bounds__(256) void k_gemm1_bucket(
    const float* __restrict__ A, const float* __restrict__ rs,
    const unsigned short* __restrict__ BT, unsigned short* __restrict__ Cm,
    const int* __restrict__ ei, const int* __restrict__ row_ptr,
    const unsigned char* __restrict__ baseb, int* __restrict__ col)
{
    __shared__ unsigned short sm[26112];   // 52224 B: GEMM tiles / bucket cursors (union)
    int b = blockIdx.x, tid = threadIdx.x;

    if (b < NBH) {
        // ---- bucket role ----
        unsigned int* cw = (unsigned int*)sm;
        for (int w = tid; w < NW; w += 256) cw[w] = 0;
        __syncthreads();
        const unsigned char* bt = baseb + (size_t)b * NN;
        int e0 = b * EPB, e1 = min(e0 + EPB, NE);
        for (int e = e0 + tid; e < e1; e += 256) {
            int s = ei[e], d = ei[NE + e];
            int sh = (d & 3) * 8;
            unsigned int old = atomicAdd(&cw[d >> 2], 1u << sh);
            col[row_ptr[d] + (int)bt[d] + ((old >> sh) & 0xff)] = s;
        }
        return;
    }

    // ---- GEMM role: t = (bf16(A_f32) @ W1) * r_out ----
    unsigned short (*As)[136] = (unsigned short(*)[136])sm;
    unsigned short (*Bs)[136] = (unsigned short(*)[136])(sm + 64 * 136);
    int lane = tid & 63, wave = tid >> 6;
    int quad = lane >> 4, l16 = lane & 15;
    int row0 = (b - NBH) * 64;

#pragma unroll
    for (int p = 0; p < 8; ++p) {
        int fid = tid + p * 256;
        int rr = fid >> 5, c = fid & 31;
        int gr = row0 + rr; if (gr > NN - 1) gr = NN - 1;
        float4 v = *(const float4*)(A + (size_t)gr * DD + c * 4);
        ushort4 u;
        u.x = f2bf(v.x); u.y = f2bf(v.y); u.z = f2bf(v.z); u.w = f2bf(v.w);
        *(ushort4*)&As[rr][c * 4] = u;
    }
#pragma unroll
    for (int p = 0; p < 8; ++p) {
        int fid = tid + p * 256;
        int rr = fid >> 4, c = fid & 15;
        *(uint4*)&Bs[rr][c * 8] = *(const uint4*)(BT + (size_t)rr * DD + c * 8);
    }
    __syncthreads();

    short8 af[4];
#pragma unroll
    for (int ks = 0; ks < 4; ++ks)
        af[ks] = *(const short8*)&As[wave * 16 + l16][ks * 32 + quad * 8];
    floatx4 acc[8];
#pragma unroll
    for (int nt = 0; nt < 8; ++nt) acc[nt] = (floatx4){0.f, 0.f, 0.f, 0.f};
#pragma unroll
    for (int ks = 0; ks < 4; ++ks) {
#pragma unroll
        for (int nt = 0; nt < 8; ++nt) {
            short8 bf = *(const short8*)&Bs[nt * 16 + l16][ks * 32 + quad * 8];
            acc[nt] = __builtin_amdgcn_mfma_f32_16x16x32_bf16(af[ks], bf, acc[nt], 0, 0, 0);
        }
    }
    int rbase = row0 + wave * 16 + quad * 4;
#pragma unroll
    for (int rr = 0; rr < 4; ++rr) {
        int gr = rbase + rr;
        if (gr < NN) {
            float s = rs[gr];
#pragma unroll
            for (int nt = 0; nt < 8; ++nt)
                Cm[(size_t)gr * DD + nt * 16 + l16] = f2bf(acc[nt][rr] * s);
        }
    }
}

// ---- MFMA GEMM (layer 2): Cm = rowscale(A_bf16 @ W2) ----
__global__ __launch_bounds__(256) void k_gemm_bf(const unsigned short* __restrict__ A,
                                                 const float* __restrict__ rs,
                                                 const unsigned short* __restrict__ BT,
                                                 unsigned short* __restrict__ Cm) {
    __shared__ unsigned short As[64][136];
    __shared__ unsigned short Bs[128][136];
    int tid = threadIdx.x, lane = tid & 63, wave = tid >> 6;
    int quad = lane >> 4, l16 = lane & 15;
    int row0 = blockIdx.x * 64;

#pragma unroll
    for (int p = 0; p < 4; ++p) {
        int fid = tid + p * 256;
        int rr = fid >> 4, c = fid & 15;
        int gr = row0 + rr; if (gr > NN - 1) gr = NN - 1;
        *(uint4*)&As[rr][c * 8] = *(const uint4*)(A + (size_t)gr * DD + c * 8);
    }
#pragma unroll
    for (int p = 0; p < 8; ++p) {
        int fid = tid + p * 256;
        int rr = fid >> 4, c = fid & 15;
        *(uint4*)&Bs[rr][c * 8] = *(const uint4*)(BT + (size_t)rr * DD + c * 8);
    }
    __syncthreads();

    short8 af[4];
#pragma unroll
    for (int ks = 0; ks < 4; ++ks)
        af[ks] = *(const short8*)&As[wave * 16 + l16][ks * 32 + quad * 8];
    floatx4 acc[8];
#pragma unroll
    for (int nt = 0; nt < 8; ++nt) acc[nt] = (floatx4){0.f, 0.f, 0.f, 0.f};
#pragma unroll
    for (int ks = 0; ks < 4; ++ks) {
#pragma unroll
        for (int nt = 0; nt < 8; ++nt) {
            short8 bf = *(const short8*)&Bs[nt * 16 + l16][ks * 32 + quad * 8];
            acc[nt] = __builtin_amdgcn_mfma_f32_16x16x32_bf16(af[ks], bf, acc[nt], 0, 0, 0);
        }
    }
    int rbase = row0 + wave * 16 + quad * 4;
#pragma unroll
    for (int rr = 0; rr < 4; ++rr) {
        int gr = rbase + rr;
        if (gr < NN) {
            float s = rs[gr];
#pragma unroll
            for (int nt = 0; nt < 8; ++nt)
                Cm[(size_t)gr * DD + nt * 16 + l16] = f2bf(acc[nt][rr] * s);
        }
    }
}

// ---- CSR aggregate + fused finalize: H[n] = bf16((sum T[s]) * r_in[n] + b) ----
// 16 lanes/node; col indices loaded DIRECTLY by all 16 lanes (same-address
// broadcast, one L1 line per sub-group) — removes the col-load->shfl latency
// hop and all LDS-pipe traffic. Accumulation order identical to prior rounds.
__global__ __launch_bounds__(256, 6) void k_aggregate(const unsigned short* __restrict__ T,
                                                      const int* __restrict__ row_ptr,
                                                      const int* __restrict__ col,
                                                      const float* __restrict__ r_in,
                                                      const float* __restrict__ b,
                                                      unsigned short* __restrict__ H) {
    int wave = threadIdx.x >> 6, lane = threadIdx.x & 63;
    int sub = lane >> 4, l16 = lane & 15;
    int node = blockIdx.x * 16 + wave * 4 + sub;
    if (node >= NN) return;
    int beg = row_ptr[node], end = row_ptr[node + 1];
    float a0 = 0.f, a1 = 0.f, a2 = 0.f, a3 = 0.f, a4 = 0.f, a5 = 0.f, a6 = 0.f, a7 = 0.f;
    const unsigned short* Tl = T + l16 * 8;
    for (int base = beg; base < end; base += 16) {
        int m = end - base; if (m > 16) m = 16;
        const int* cb = col + base;
        int j = 0;
        for (; j + 4 <= m; j += 4) {
            int s0 = cb[j], s1 = cb[j + 1], s2 = cb[j + 2], s3 = cb[j + 3];
            uint4 v0 = *(const uint4*)(Tl + (size_t)s0 * DD);
            uint4 v1 = *(const uint4*)(Tl + (size_t)s1 * DD);
            uint4 v2 = *(const uint4*)(Tl + (size_t)s2 * DD);
            uint4 v3 = *(const uint4*)(Tl + (size_t)s3 * DD);
            a0 += bf2f(v0.x & 0xffff) + bf2f(v1.x & 0xffff) + bf2f(v2.x & 0xffff) + bf2f(v3.x & 0xffff);
            a1 += bf2f(v0.x >> 16)    + bf2f(v1.x >> 16)    + bf2f(v2.x >> 16)    + bf2f(v3.x >> 16);
            a2 += bf2f(v0.y & 0xffff) + bf2f(v1.y & 0xffff) + bf2f(v2.y & 0xffff) + bf2f(v3.y & 0xffff);
            a3 += bf2f(v0.y >> 16)    + bf2f(v1.y >> 16)    + bf2f(v2.y >> 16)    + bf2f(v3.y >> 16);
            a4 += bf2f(v0.z & 0xffff) + bf2f(v1.z & 0xffff) + bf2f(v2.z & 0xffff) + bf2f(v3.z & 0xffff);
            a5 += bf2f(v0.z >> 16)    + bf2f(v1.z >> 16)    + bf2f(v2.z >> 16)    + bf2f(v3.z >> 16);
            a6 += bf2f(v0.w & 0xffff) + bf2f(v1.w & 0xffff) + bf2f(v2.w & 0xffff) + bf2f(v3.w & 0xffff);
            a7 += bf2f(v0.w >> 16)    + bf2f(v1.w >> 16)    + bf2f(v2.w >> 16)    + bf2f(v3.w >> 16);
        }
        for (; j < m; ++j) {
            int s0 = cb[j];
            uint4 v0 = *(const uint4*)(Tl + (size_t)s0 * DD);
            a0 += bf2f(v0.x & 0xffff); a1 += bf2f(v0.x >> 16);
            a2 += bf2f(v0.y & 0xffff); a3 += bf2f(v0.y >> 16);
            a4 += bf2f(v0.z & 0xffff); a5 += bf2f(v0.z >> 16);
            a6 += bf2f(v0.w & 0xffff); a7 += bf2f(v0.w >> 16);
        }
    }
    float rv = r_in[node];
    float4 bl = *(const float4*)(b + l16 * 8);
    float4 bh = *(const float4*)(b + l16 * 8 + 4);
    uint4 w;
    w.x = (unsigned int)f2bf(a0 * rv + bl.x) | ((unsigned int)f2bf(a1 * rv + bl.y) << 16);
    w.y = (unsigned int)f2bf(a2 * rv + bl.z) | ((unsigned int)f2bf(a3 * rv + bl.w) << 16);
    w.z = (unsigned int)f2bf(a4 * rv + bh.x) | ((unsigned int)f2bf(a5 * rv + bh.y) << 16);
    w.w = (unsigned int)f2bf(a6 * rv + bh.z) | ((unsigned int)f2bf(a7 * rv + bh.w) << 16);
    *(uint4*)(H + (size_t)node * DD + l16 * 8) = w;
}

// ---- MFMA MLP: P[n] = softmax(relu(h2[n]@dW + db)@oW + ob) ----
__global__ __launch_bounds__(256) void k_mlp_mfma(const unsigned short* __restrict__ H2,
                                                  const unsigned short* __restrict__ BTd,
                                                  const float* __restrict__ db,
                                                  const float* __restrict__ oW,
                                                  const float* __restrict__ ob,
                                                  float* __restrict__ P) {
    __shared__ unsigned short As[64][136];
    __shared__ unsigned short Bs[128][136];
    int tid = threadIdx.x, lane = tid & 63, wave = tid >> 6;
    int quad = lane >> 4, l16 = lane & 15;
    int row0 = blockIdx.x * 64;
#pragma unroll
    for (int p = 0; p < 4; ++p) {
        int fid = tid + p * 256;
        int rr = fid >> 4, c = fid & 15;
        int gr = row0 + rr; if (gr > NN - 1) gr = NN - 1;
        *(uint4*)&As[rr][c * 8] = *(const uint4*)(H2 + (size_t)gr * DD + c * 8);
    }
    short8 af[4];
    floatx4 acc[16];
#pragma unroll
    for (int i = 0; i < 16; ++i) acc[i] = (floatx4){0.f, 0.f, 0.f, 0.f};

    for (int ch = 0; ch < 2; ++ch) {
        __syncthreads();
#pragma unroll
        for (int p = 0; p < 8; ++p) {
            int fid = tid + p * 256;
            int rr = fid >> 4, c = fid & 15;
            *(uint4*)&Bs[rr][c * 8] = *(const uint4*)(BTd + (size_t)(ch * 128 + rr) * DD + c * 8);
        }
        __syncthreads();
        if (ch == 0) {
#pragma unroll
            for (int ks = 0; ks < 4; ++ks)
                af[ks] = *(const short8*)&As[wave * 16 + l16][ks * 32 + quad * 8];
        }
#pragma unroll
        for (int ks = 0; ks < 4; ++ks) {
#pragma unroll
            for (int nt = 0; nt < 8; ++nt) {
                short8 bf = *(const short8*)&Bs[nt * 16 + l16][ks * 32 + quad * 8];
                acc[ch * 8 + nt] =
                    __builtin_amdgcn_mfma_f32_16x16x32_bf16(af[ks], bf, acc[ch * 8 + nt], 0, 0, 0);
            }
        }
    }
    int rbase = row0 + wave * 16 + quad * 4;
#pragma unroll
    for (int rr = 0; rr < 4; ++rr) {
        float p0 = 0.f, p1 = 0.f;
#pragma unroll
        for (int ch = 0; ch < 2; ++ch) {
#pragma unroll
            for (int nt = 0; nt < 8; ++nt) {
                int colc = ch * 128 + nt * 16 + l16;
                float h = acc[ch * 8 + nt][rr] + db[colc];
                h = fmaxf(h, 0.f);
                p0 += h * oW[2 * colc];
                p1 += h * oW[2 * colc + 1];
            }
        }
#pragma unroll
        for (int m = 8; m >= 1; m >>= 1) {
            p0 += __shfl_xor(p0, m, 16);
            p1 += __shfl_xor(p1, m, 16);
        }
        if (l16 == 0) {
            int gr = rbase + rr;
            if (gr < NN) {
                float l0 = p0 + ob[0], l1 = p1 + ob[1];
                float mx = fmaxf(l0, l1);
                float e0 = __expf(l0 - mx), e1 = __expf(l1 - mx);
                float inv = 1.f / (e0 + e1);
                float2 pr = {e0 * inv, e1 * inv};
                *(float2*)(P + 2 * gr) = pr;
            }
        }
    }
}

// ---- final gather ----
__global__ void k_gather(const int* __restrict__ sidx, const int* __restrict__ oe,
                         const float* __restrict__ P, float* __restrict__ out) {
    int i = blockIdx.x * 256 + threadIdx.x;
    if (i >= NS) return;
    int node = oe[sidx[i]];
    float2 v = *(const float2*)(P + 2 * node);
    *(float2*)(out + 2 * i) = v;
}

extern "C" void kernel_launch(void* const* d_in, const int* in_sizes, int n_in,
                              void* d_out, int out_size, void* d_ws, size_t ws_size,
                              hipStream_t stream) {
    const float* node_state = (const float*)d_in[0];
    const int* ei   = (const int*)d_in[1];
    const int* oe   = (const int*)d_in[2];
    const int* sidx = (const int*)d_in[3];
    const float* W1 = (const float*)d_in[4];
    const float* b1 = (const float*)d_in[5];
    const float* W2 = (const float*)d_in[6];
    const float* b2 = (const float*)d_in[7];
    const float* dW = (const float*)d_in[8];
    const float* db = (const float*)d_in[9];
    const float* oW = (const float*)d_in[10];
    const float* ob = (const float*)d_in[11];
    float* out = (float*)d_out;

    char* ws = (char*)d_ws;
    size_t off = 0;
    auto carve = [&](size_t bytes) -> char* {
        char* p = ws + off;
        off = (off + bytes + 255) & ~(size_t)255;
        return p;
    };
    float* r       = (float*)carve((size_t)2 * NN * 4);
    int*   row_ptr = (int*)carve((size_t)(NN + 1) * 4);
    int*   col     = (int*)carve((size_t)NE * 4);
    unsigned int* P_hist = (unsigned int*)carve((size_t)2 * NBH * NW * 4);
    unsigned char* baseb = (unsigned char*)carve((size_t)NBH * NN);
    unsigned long long* status = (unsigned long long*)carve(64 * 8);
    unsigned short* t   = (unsigned short*)carve((size_t)NN * DD * 2);
    unsigned short* h   = (unsigned short*)carve((size_t)NN * DD * 2);
    unsigned short* BT1 = (unsigned short*)carve((size_t)DD * DD * 2);
    unsigned short* BT2 = (unsigned short*)carve((size_t)DD * DD * 2);
    unsigned short* BTd = (unsigned short*)carve((size_t)DD * NU * 2);
    float* P = (float*)t;   // alias: t dead after second aggregate

    float* r_out = r;
    float* r_in  = r + NN;

    // CSR build — no global atomics; weight cast folded into k_hist;
    // baseb emitted inline during k_mid's column reduce (no phase-D pass)
    k_hist<<<dim3(NBH, 2), 512, 0, stream>>>(ei, P_hist, status, W1, W2, dW,
                                             BT1, BT2, BTd);
    k_mid<<<2 * NSCAN, 256, 0, stream>>>(P_hist, r, row_ptr, baseb, status);

    // bucket + layer-1 GEMM in one wide kernel (independent given k_mid)
    k_gemm1_bucket<<<NBH + NB64, 256, 0, stream>>>(node_state, r_out, BT1, t,
                                                   ei, row_ptr, baseb, col);
    k_aggregate<<<(NN + 15) / 16, 256, 0, stream>>>(t, row_ptr, col, r_in, b1, h);

    // layer 2
    k_gemm_bf<<<NB64, 256, 0, stream>>>(h, r_out, BT2, t);
    k_aggregate<<<(NN + 15) / 16, 256, 0, stream>>>(t, row_ptr, col, r_in, b2, h);

    // per-node MLP + softmax, then gather
    k_mlp_mfma<<<NB64, 256, 0, stream>>>(h, BTd, db, oW, ob, P);
    k_gather<<<(NS + 255) / 256, 256, 0, stream>>>(sidx, oe, P, out);
}